// Round 1
// 138.850 us; speedup vs baseline: 1.0213x; 1.0213x over previous
//
#include <hip/hip_runtime.h>

// LocalAttention, MFMA bf16, round 8 = occupancy push.
// B=4, L=2048, H=16, E=D=64, window=64. fp32 in/out; bf16 MFMA; fp32 accumulate.
//
// Round-7 post-mortem: VGPR_Count=68 proved sched_barrier(0) never batched the
// 28 loads -- the conditional V/K bounds checks split staging into multiple
// basic blocks, which the scheduler fence cannot span. All counters
// (MfmaUtil 2.4%, VALUBusy 22%, HBM 33%, Occupancy 25%) say latency-bound with
// poor load duty cycle. Little's law: ~9 KB/CU in flight sustains our HBM
// share; even chunked loads x12 waves exceeds that -- the limiter is the
// fraction of time ANY loads are in flight. Fix = more resident blocks:
//
//   1. Overlay P onto Ks (Ks is dead after the QK MFMAs; one extra
//      __syncthreads() between QK and P-write). LDS 51200 -> 37888 B.
//   2. __launch_bounds__(256, 4): 4 blocks/CU = 16 waves/CU (was 3/12).
//      VGPR cap 128 (was 170); current use 68 leaves headroom.
//   3. Branchless staging: clamp key index to [0, L-1], load unconditionally.
//      Out-of-window scores are masked by INDEX in softmax (data-independent),
//      and invalid V rows multiply exactly-0 P. Single basic block -> the
//      fence after K+V issue really holds 16 loads (~64 regs) in flight.
//
// Structure otherwise identical:
//   - K staged coalesced -> LDS natural layout [key][dim].
//   - V staged (2 keys x 16-dim quarters per lane) -> LDS transposed [dim][key].
//   - Q A-frags direct from global (each Q row read once).
//   - Per-wave P -> LDS (overlaid on Ks); 5 QK + 12 PV MFMAs per wave.
// LDS = Ks 128x72 (shared with P 4x16x104) + Vt 64x152 = 37888 B -> 4 blocks/CU.

#define B_ 4
#define L_ 2048
#define H_ 16
#define E_ 64
#define D_ 64
#define KS_STRIDE 72
#define VT_STRIDE 152
#define P_STRIDE 104

typedef __attribute__((ext_vector_type(8))) short short8;
typedef __attribute__((ext_vector_type(4))) float f32x4;

__device__ __forceinline__ unsigned int f2bf(float x) {
  unsigned int b = __float_as_uint(x);
  b += 0x7fffu + ((b >> 16) & 1u);   // RNE to bf16
  return b >> 16;
}
__device__ __forceinline__ unsigned int pack2(float a, float b) {
  return f2bf(a) | (f2bf(b) << 16);
}
__device__ __forceinline__ short8 pack8(const float4& a, const float4& b) {
  union { short8 s; uint4 u; } r;
  r.u = make_uint4(pack2(a.x, a.y), pack2(a.z, a.w), pack2(b.x, b.y), pack2(b.z, b.w));
  return r.s;
}
__device__ __forceinline__ int clampL(int k) {
  return k < 0 ? 0 : (k > (L_ - 1) ? (L_ - 1) : k);
}

__global__ __launch_bounds__(256, 4)
void local_attn_mfma(const float* __restrict__ qg,
                     const float* __restrict__ kg,
                     const float* __restrict__ vg,
                     float* __restrict__ og) {
  // Ks doubles as the per-wave P tile after the second barrier (QK is done
  // with it by then). P needs 4*16*104*2 = 13312 B <= 18432 B.
  __shared__ __align__(16) unsigned short Ks[128 * KS_STRIDE];   // [key_rel][dim]
  __shared__ __align__(16) unsigned short Vt[64 * VT_STRIDE];    // [dim][key_rel]

  const int t = threadIdx.x;
  const int q0 = blockIdx.x * 64;
  const int h = blockIdx.y;
  const int b = blockIdx.z;
  const int kstart = q0 - 32;
  const int wave = t >> 6;
  const int lane = t & 63;
  const int col16 = lane & 15;
  const int quad = lane >> 4;

  // ---- Issue K + V global loads, branchless (clamped addresses) ----
  float4 kf[8];
  #pragma unroll
  for (int it = 0; it < 8; ++it) {
    int cid = t + it * 256;            // 128 rows x 16 float4-chunks
    int row = cid >> 4, ch = cid & 15;
    int key = clampL(kstart + row);
    kf[it] = *(const float4*)(kg + ((size_t)(b * L_ + key) * H_ + h) * E_ + ch * 4);
  }
  const int kp = t >> 2;               // key pair -> keys kstart+2kp, +2kp+1
  const int dq = t & 3;                // dim quarter: dims dq*16 .. +15
  float4 va[4], vc[4];
  {
    int k0 = clampL(kstart + 2 * kp);
    int k1 = clampL(kstart + 2 * kp + 1);
    const float* p0 = vg + ((size_t)(b * L_ + k0) * H_ + h) * D_ + dq * 16;
    const float* p1 = vg + ((size_t)(b * L_ + k1) * H_ + h) * D_ + dq * 16;
    #pragma unroll
    for (int i = 0; i < 4; ++i) va[i] = *(const float4*)(p0 + i * 4);
    #pragma unroll
    for (int i = 0; i < 4; ++i) vc[i] = *(const float4*)(p1 + i * 4);
  }

  // ---- FENCE: all 24 K/V loads (96 regs) issued before any pack/wait.
  //      Q loads (16 regs) ride with the packs; peak live ~110 < 128 cap. ----
  __builtin_amdgcn_sched_barrier(0);

  float4 qf0, qf1, qf2, qf3;
  {
    const float* p = qg + ((size_t)(b * L_ + q0 + wave * 16 + col16) * H_ + h) * E_ + quad * 8;
    qf0 = *(const float4*)p;
    qf1 = *(const float4*)(p + 4);
    qf2 = *(const float4*)(p + 32);
    qf3 = *(const float4*)(p + 36);
  }

  // ---- Pack + LDS writes ----
  #pragma unroll
  for (int it = 0; it < 8; ++it) {
    int cid = t + it * 256;
    int row = cid >> 4, ch = cid & 15;
    float4 f = kf[it];
    *(uint2*)&Ks[row * KS_STRIDE + ch * 4] = make_uint2(pack2(f.x, f.y), pack2(f.z, f.w));
  }
  #pragma unroll
  for (int i = 0; i < 4; ++i) {
    float av[4] = {va[i].x, va[i].y, va[i].z, va[i].w};
    float cv[4] = {vc[i].x, vc[i].y, vc[i].z, vc[i].w};
    #pragma unroll
    for (int j = 0; j < 4; ++j) {
      int d = dq * 16 + i * 4 + j;
      *(unsigned int*)&Vt[d * VT_STRIDE + 2 * kp] = pack2(av[j], cv[j]);
    }
  }
  // zero pad Vt key cols 128..143 (PV K-overhang reads them; P there is 0)
  *(uint2*)&Vt[(t >> 2) * VT_STRIDE + 128 + (t & 3) * 4] = make_uint2(0u, 0u);

  const short8 qa0 = pack8(qf0, qf1);
  const short8 qa1 = pack8(qf2, qf3);
  __syncthreads();

  // ---- QK: 5 key-tiles; B-frags from Ks (ds_read_b128) ----
  f32x4 acc[5];
  #pragma unroll
  for (int tt = 0; tt < 5; ++tt) {
    int krow = wave * 16 + tt * 16 + col16;     // B: n=key, k=quad*8+j (E-dim)
    short8 b0 = *(const short8*)&Ks[krow * KS_STRIDE + quad * 8];
    short8 b1 = *(const short8*)&Ks[krow * KS_STRIDE + quad * 8 + 32];
    f32x4 c = {0.f, 0.f, 0.f, 0.f};
    c = __builtin_amdgcn_mfma_f32_16x16x32_bf16(qa0, b0, c, 0, 0, 0);
    c = __builtin_amdgcn_mfma_f32_16x16x32_bf16(qa1, b1, c, 0, 0, 0);
    acc[tt] = c;
  }

  // ---- Mask + softmax in registers. C layout: row=quad*4+r, col=col16 ----
  // Mask is INDEX-based, so clamped-garbage K rows are neutralized here.
  #pragma unroll
  for (int r = 0; r < 4; ++r) {
    const int row_loc = quad * 4 + r;
    float x[5];
    #pragma unroll
    for (int tt = 0; tt < 5; ++tt) {
      int c_loc = tt * 16 + col16;                    // key rel to M-tile start
      int gkey = kstart + wave * 16 + c_loc;          // global key
      bool ok = (c_loc >= row_loc) && (c_loc < row_loc + 64) && (gkey >= 0) && (gkey < L_);
      x[tt] = ok ? acc[tt][r] * 0.125f : -1e30f;      // scale = 1/sqrt(64)
    }
    float m = fmaxf(fmaxf(fmaxf(x[0], x[1]), fmaxf(x[2], x[3])), x[4]);
    m = fmaxf(m, __shfl_xor(m, 1));
    m = fmaxf(m, __shfl_xor(m, 2));
    m = fmaxf(m, __shfl_xor(m, 4));
    m = fmaxf(m, __shfl_xor(m, 8));
    float s = 0.f;
    #pragma unroll
    for (int tt = 0; tt < 5; ++tt) { x[tt] = __expf(x[tt] - m); s += x[tt]; }
    s += __shfl_xor(s, 1);
    s += __shfl_xor(s, 2);
    s += __shfl_xor(s, 4);
    s += __shfl_xor(s, 8);
    float inv = 1.0f / s;              // >= 32 valid keys -> s >= 1
    #pragma unroll
    for (int tt = 0; tt < 5; ++tt) acc[tt][r] = x[tt] * inv;
  }

  // ---- Barrier 2: all waves done reading Ks; its LDS now holds P ----
  __syncthreads();

  // ---- P -> LDS (bf16, A-layout target), zero-pad cols 80..95 ----
  unsigned short* Pw = &Ks[wave * 16 * P_STRIDE];
  *(uint2*)&Pw[col16 * P_STRIDE + 80 + quad * 4] = make_uint2(0u, 0u);
  #pragma unroll
  for (int tt = 0; tt < 5; ++tt)
    #pragma unroll
    for (int r = 0; r < 4; ++r)
      Pw[(quad * 4 + r) * P_STRIDE + tt * 16 + col16] = (unsigned short)f2bf(acc[tt][r]);

  // ---- PV: A=P[16 x 96], B=Vt keys [wave*16, wave*16+96) x 64 dims ----
  f32x4 oacc[4];
  #pragma unroll
  for (int nt = 0; nt < 4; ++nt) oacc[nt] = (f32x4){0.f, 0.f, 0.f, 0.f};
  #pragma unroll
  for (int ks = 0; ks < 3; ++ks) {
    short8 pa = *(const short8*)&Pw[col16 * P_STRIDE + ks * 32 + quad * 8];
    #pragma unroll
    for (int nt = 0; nt < 4; ++nt) {
      short8 vb = *(const short8*)&Vt[(nt * 16 + col16) * VT_STRIDE + wave * 16 + ks * 32 + quad * 8];
      oacc[nt] = __builtin_amdgcn_mfma_f32_16x16x32_bf16(pa, vb, oacc[nt], 0, 0, 0);
    }
  }

  // ---- Store O (fp32). C layout: row=quad*4+r (query), col=col16 (dim base) ----
  #pragma unroll
  for (int r = 0; r < 4; ++r) {
    int q = q0 + wave * 16 + quad * 4 + r;
    float* orow = og + ((size_t)(b * L_ + q) * H_ + h) * D_;
    #pragma unroll
    for (int nt = 0; nt < 4; ++nt)
      orow[nt * 16 + col16] = oacc[nt][r];
  }
}

extern "C" void kernel_launch(void* const* d_in, const int* in_sizes, int n_in,
                              void* d_out, int out_size, void* d_ws, size_t ws_size,
                              hipStream_t stream) {
  const float* q = (const float*)d_in[0];
  const float* k = (const float*)d_in[1];
  const float* v = (const float*)d_in[2];
  float* o = (float*)d_out;
  dim3 grid(L_ / 64, H_, B_);
  local_attn_mfma<<<grid, dim3(256), 0, stream>>>(q, k, v, o);
}

// Round 2
// 138.203 us; speedup vs baseline: 1.0261x; 1.0047x over previous
//
#include <hip/hip_runtime.h>

// LocalAttention, MFMA bf16, round 9 = force load batching via asm data anchor.
// B=4, L=2048, H=16, E=D=64, window=64. fp32 in/out; bf16 MFMA; fp32 accumulate.
//
// Round-8 post-mortem: VGPR_Count dropped to 52 -- sched_barrier(0) STILL did
// not batch the staging loads. Mechanism: llvm.amdgcn.sched.barrier is
// IntrNoMem, so IR-level passes legally sink loads toward their uses before
// the machine scheduler ever sees the fence. Evidence: VGPR 68 (r7) -> 52 (r8)
// while occupancy rose (25->30%) and BW stayed flat (2.6->2.8 TB/s).
// The staging phase is ~4-6 serialized HBM round-trips per block.
//
// Fix: create a DATA dependence no pass can defeat. Issue all 16 K/V loads
// into f32x4 regs (64 VGPRs), then one asm volatile consuming every loaded
// vector. Loads cannot sink below a use of their result -> all 16 issue
// back-to-back, single vmcnt wait at the asm. In-flight bytes/wave: ~2 KB ->
// 16 KB. Peak live ~100 VGPR < 128 cap (launch_bounds 256,4) -> no spill.
// Q's 4 loads ride after the anchor, hidden under the K/V packs.
//
// Structure otherwise identical to round 8:
//   - K staged coalesced -> LDS natural layout [key][dim], bf16.
//   - V staged (2 keys x 16-dim quarters per lane) -> LDS transposed [dim][key].
//   - Q A-frags direct from global; branchless clamped staging addresses
//     (out-of-window masked by INDEX in softmax; invalid V rows hit P==0).
//   - P overlaid on Ks after QK (extra barrier). LDS 37888 B -> 4 blocks/CU.

#define B_ 4
#define L_ 2048
#define H_ 16
#define E_ 64
#define D_ 64
#define KS_STRIDE 72
#define VT_STRIDE 152
#define P_STRIDE 104

typedef __attribute__((ext_vector_type(8))) short short8;
typedef __attribute__((ext_vector_type(4))) float f32x4;

__device__ __forceinline__ unsigned int f2bf(float x) {
  unsigned int b = __float_as_uint(x);
  b += 0x7fffu + ((b >> 16) & 1u);   // RNE to bf16
  return b >> 16;
}
__device__ __forceinline__ unsigned int pack2(float a, float b) {
  return f2bf(a) | (f2bf(b) << 16);
}
__device__ __forceinline__ short8 pack8(const f32x4& a, const f32x4& b) {
  union { short8 s; uint4 u; } r;
  r.u = make_uint4(pack2(a[0], a[1]), pack2(a[2], a[3]),
                   pack2(b[0], b[1]), pack2(b[2], b[3]));
  return r.s;
}
__device__ __forceinline__ int clampL(int k) {
  return k < 0 ? 0 : (k > (L_ - 1) ? (L_ - 1) : k);
}

__global__ __launch_bounds__(256, 4)
void local_attn_mfma(const float* __restrict__ qg,
                     const float* __restrict__ kg,
                     const float* __restrict__ vg,
                     float* __restrict__ og) {
  // Ks doubles as the per-wave P tile after the second barrier (QK is done
  // with it by then). P needs 4*16*104*2 = 13312 B <= 18432 B.
  __shared__ __align__(16) unsigned short Ks[128 * KS_STRIDE];   // [key_rel][dim]
  __shared__ __align__(16) unsigned short Vt[64 * VT_STRIDE];    // [dim][key_rel]

  const int t = threadIdx.x;
  const int q0 = blockIdx.x * 64;
  const int h = blockIdx.y;
  const int b = blockIdx.z;
  const int kstart = q0 - 32;
  const int wave = t >> 6;
  const int lane = t & 63;
  const int col16 = lane & 15;
  const int quad = lane >> 4;

  // ---- Issue K + V global loads, branchless (clamped addresses) ----
  f32x4 kf[8];
  #pragma unroll
  for (int it = 0; it < 8; ++it) {
    int cid = t + it * 256;            // 128 rows x 16 float4-chunks
    int row = cid >> 4, ch = cid & 15;
    int key = clampL(kstart + row);
    kf[it] = *(const f32x4*)(kg + ((size_t)(b * L_ + key) * H_ + h) * E_ + ch * 4);
  }
  const int kp = t >> 2;               // key pair -> keys kstart+2kp, +2kp+1
  const int dq = t & 3;                // dim quarter: dims dq*16 .. +15
  f32x4 va[4], vc[4];
  {
    int k0 = clampL(kstart + 2 * kp);
    int k1 = clampL(kstart + 2 * kp + 1);
    const float* p0 = vg + ((size_t)(b * L_ + k0) * H_ + h) * D_ + dq * 16;
    const float* p1 = vg + ((size_t)(b * L_ + k1) * H_ + h) * D_ + dq * 16;
    #pragma unroll
    for (int i = 0; i < 4; ++i) va[i] = *(const f32x4*)(p0 + i * 4);
    #pragma unroll
    for (int i = 0; i < 4; ++i) vc[i] = *(const f32x4*)(p1 + i * 4);
  }

  // ---- ANCHOR: a real data dependence on every loaded vector. IR passes
  //      cannot sink a load below a use of its result; the scheduler cannot
  //      either. All 16 loads issue first, one vmcnt wait lands here. ----
  asm volatile("" ::
      "v"(kf[0]), "v"(kf[1]), "v"(kf[2]), "v"(kf[3]),
      "v"(kf[4]), "v"(kf[5]), "v"(kf[6]), "v"(kf[7]),
      "v"(va[0]), "v"(va[1]), "v"(va[2]), "v"(va[3]),
      "v"(vc[0]), "v"(vc[1]), "v"(vc[2]), "v"(vc[3]));
  __builtin_amdgcn_sched_barrier(0);

  f32x4 qf0, qf1, qf2, qf3;
  {
    const float* p = qg + ((size_t)(b * L_ + q0 + wave * 16 + col16) * H_ + h) * E_ + quad * 8;
    qf0 = *(const f32x4*)p;
    qf1 = *(const f32x4*)(p + 4);
    qf2 = *(const f32x4*)(p + 32);
    qf3 = *(const f32x4*)(p + 36);
  }

  // ---- Pack + LDS writes ----
  #pragma unroll
  for (int it = 0; it < 8; ++it) {
    int cid = t + it * 256;
    int row = cid >> 4, ch = cid & 15;
    f32x4 f = kf[it];
    *(uint2*)&Ks[row * KS_STRIDE + ch * 4] =
        make_uint2(pack2(f[0], f[1]), pack2(f[2], f[3]));
  }
  #pragma unroll
  for (int i = 0; i < 4; ++i) {
    #pragma unroll
    for (int j = 0; j < 4; ++j) {
      int d = dq * 16 + i * 4 + j;
      *(unsigned int*)&Vt[d * VT_STRIDE + 2 * kp] = pack2(va[i][j], vc[i][j]);
    }
  }
  // zero pad Vt key cols 128..143 (PV K-overhang reads them; P there is 0)
  *(uint2*)&Vt[(t >> 2) * VT_STRIDE + 128 + (t & 3) * 4] = make_uint2(0u, 0u);

  const short8 qa0 = pack8(qf0, qf1);
  const short8 qa1 = pack8(qf2, qf3);
  __syncthreads();

  // ---- QK: 5 key-tiles; B-frags from Ks (ds_read_b128) ----
  f32x4 acc[5];
  #pragma unroll
  for (int tt = 0; tt < 5; ++tt) {
    int krow = wave * 16 + tt * 16 + col16;     // B: n=key, k=quad*8+j (E-dim)
    short8 b0 = *(const short8*)&Ks[krow * KS_STRIDE + quad * 8];
    short8 b1 = *(const short8*)&Ks[krow * KS_STRIDE + quad * 8 + 32];
    f32x4 c = {0.f, 0.f, 0.f, 0.f};
    c = __builtin_amdgcn_mfma_f32_16x16x32_bf16(qa0, b0, c, 0, 0, 0);
    c = __builtin_amdgcn_mfma_f32_16x16x32_bf16(qa1, b1, c, 0, 0, 0);
    acc[tt] = c;
  }

  // ---- Mask + softmax in registers. C layout: row=quad*4+r, col=col16 ----
  // Mask is INDEX-based, so clamped-garbage K rows are neutralized here.
  #pragma unroll
  for (int r = 0; r < 4; ++r) {
    const int row_loc = quad * 4 + r;
    float x[5];
    #pragma unroll
    for (int tt = 0; tt < 5; ++tt) {
      int c_loc = tt * 16 + col16;                    // key rel to M-tile start
      int gkey = kstart + wave * 16 + c_loc;          // global key
      bool ok = (c_loc >= row_loc) && (c_loc < row_loc + 64) && (gkey >= 0) && (gkey < L_);
      x[tt] = ok ? acc[tt][r] * 0.125f : -1e30f;      // scale = 1/sqrt(64)
    }
    float m = fmaxf(fmaxf(fmaxf(x[0], x[1]), fmaxf(x[2], x[3])), x[4]);
    m = fmaxf(m, __shfl_xor(m, 1));
    m = fmaxf(m, __shfl_xor(m, 2));
    m = fmaxf(m, __shfl_xor(m, 4));
    m = fmaxf(m, __shfl_xor(m, 8));
    float s = 0.f;
    #pragma unroll
    for (int tt = 0; tt < 5; ++tt) { x[tt] = __expf(x[tt] - m); s += x[tt]; }
    s += __shfl_xor(s, 1);
    s += __shfl_xor(s, 2);
    s += __shfl_xor(s, 4);
    s += __shfl_xor(s, 8);
    float inv = 1.0f / s;              // >= 32 valid keys -> s >= 1
    #pragma unroll
    for (int tt = 0; tt < 5; ++tt) acc[tt][r] = x[tt] * inv;
  }

  // ---- Barrier 2: all waves done reading Ks; its LDS now holds P ----
  __syncthreads();

  // ---- P -> LDS (bf16, A-layout target), zero-pad cols 80..95 ----
  unsigned short* Pw = &Ks[wave * 16 * P_STRIDE];
  *(uint2*)&Pw[col16 * P_STRIDE + 80 + quad * 4] = make_uint2(0u, 0u);
  #pragma unroll
  for (int tt = 0; tt < 5; ++tt)
    #pragma unroll
    for (int r = 0; r < 4; ++r)
      Pw[(quad * 4 + r) * P_STRIDE + tt * 16 + col16] = (unsigned short)f2bf(acc[tt][r]);

  // ---- PV: A=P[16 x 96], B=Vt keys [wave*16, wave*16+96) x 64 dims ----
  f32x4 oacc[4];
  #pragma unroll
  for (int nt = 0; nt < 4; ++nt) oacc[nt] = (f32x4){0.f, 0.f, 0.f, 0.f};
  #pragma unroll
  for (int ks = 0; ks < 3; ++ks) {
    short8 pa = *(const short8*)&Pw[col16 * P_STRIDE + ks * 32 + quad * 8];
    #pragma unroll
    for (int nt = 0; nt < 4; ++nt) {
      short8 vb = *(const short8*)&Vt[(nt * 16 + col16) * VT_STRIDE + wave * 16 + ks * 32 + quad * 8];
      oacc[nt] = __builtin_amdgcn_mfma_f32_16x16x32_bf16(pa, vb, oacc[nt], 0, 0, 0);
    }
  }

  // ---- Store O (fp32). C layout: row=quad*4+r (query), col=col16 (dim base) ----
  #pragma unroll
  for (int r = 0; r < 4; ++r) {
    int q = q0 + wave * 16 + quad * 4 + r;
    float* orow = og + ((size_t)(b * L_ + q) * H_ + h) * D_;
    #pragma unroll
    for (int nt = 0; nt < 4; ++nt)
      orow[nt * 16 + col16] = oacc[nt][r];
  }
}

extern "C" void kernel_launch(void* const* d_in, const int* in_sizes, int n_in,
                              void* d_out, int out_size, void* d_ws, size_t ws_size,
                              hipStream_t stream) {
  const float* q = (const float*)d_in[0];
  const float* k = (const float*)d_in[1];
  const float* v = (const float*)d_in[2];
  float* o = (float*)d_out;
  dim3 grid(L_ / 64, H_, B_);
  local_attn_mfma<<<grid, dim3(256), 0, stream>>>(q, k, v, o);
}